// Round 2
// baseline (265.568 us; speedup 1.0000x reference)
//
#include <hip/hip_runtime.h>

#define NCLS 21
#define HW (512 * 512)
#define NP (HW / 2)          // 131072 pixel-pairs per image
#define BATCH 8
#define BLOCK 256
#define BPI (NP / BLOCK)     // 512 blocks per image
#define NB (BATCH * BPI)     // 4096 partial columns

// ws layout (floats): ws[r * NB + col], r in [0,42)
//   r <  21 : union partial for class r
//   r >= 21 : intersect partial for class r-21
//   col = b * BPI + blk  (each block overwrites its own column; no pre-zero needed)

__global__ __launch_bounds__(BLOCK) void iou_partial_kernel(
        const float* __restrict__ in,   // [B, C, H, W] fp32 logits
        const int*   __restrict__ tgt,  // [B, H, W] int32 labels
        float* __restrict__ ws) {
    const int b   = blockIdx.y;
    const int blk = blockIdx.x;
    const float2* __restrict__ in2 = (const float2*)(in + (size_t)b * NCLS * HW);
    const int2*   __restrict__ tb2 = (const int2*)(tgt + (size_t)b * HW);

    __shared__ float s_u[NCLS];
    __shared__ float s_i[NCLS];
    if (threadIdx.x < NCLS) { s_u[threadIdx.x] = 0.0f; s_i[threadIdx.x] = 0.0f; }
    __syncthreads();

    const int p = blk * BLOCK + threadIdx.x;   // pair index (coalesced, 8 B/lane)

    const int2 t2 = tb2[p];
    float2 x[NCLS];
    #pragma unroll
    for (int c = 0; c < NCLS; ++c)
        x[c] = in2[(size_t)c * NP + p];

    const int t[2] = {t2.x, t2.y};
    #pragma unroll
    for (int j = 0; j < 2; ++j) {
        const int tj = t[j];
        // pass 1: max + argmax (strict >, first index on tie)
        float m  = (j == 0) ? x[0].x : x[0].y;
        int   aj = 0;
        #pragma unroll
        for (int c = 1; c < NCLS; ++c) {
            const float v = (j == 0) ? x[c].x : x[c].y;
            const bool g = v > m;
            aj = g ? c : aj;
            m  = g ? v : m;
        }
        // pass 2: sum of exp + select e_target in the same sweep
        float s  = 0.0f;
        float et = 0.0f;
        #pragma unroll
        for (int c = 0; c < NCLS; ++c) {
            const float v = (j == 0) ? x[c].x : x[c].y;
            const float e = __expf(v - m);
            s += e;
            et = (c == tj) ? e : et;
        }
        const float p_pred = 1.0f / s;        // exp(m-m)/s
        const float p_t    = et * p_pred;
        const bool  eq = (tj == aj);
        // union 2->1 clamp: if eq, one union add + one intersect add;
        // else two union adds. Exactly 2 LDS atomics/pixel, branchless.
        atomicAdd(&s_u[aj], p_pred);
        atomicAdd(eq ? &s_i[aj] : &s_u[tj], eq ? p_pred : p_t);
    }

    __syncthreads();
    // Non-atomic per-block partial write: 42 scattered dwords per block.
    if (threadIdx.x < 2 * NCLS) {
        const float v = (threadIdx.x < NCLS) ? s_u[threadIdx.x]
                                             : s_i[threadIdx.x - NCLS];
        ws[(size_t)threadIdx.x * NB + b * BPI + blk] = v;
    }
}

#define FBLOCK 1024

__global__ __launch_bounds__(FBLOCK) void finalize_kernel(
        const float* __restrict__ ws, float* __restrict__ out) {
    const int tid = threadIdx.x;
    float val = 0.0f;
    if (tid < BATCH * NCLS * 4) {
        const int g   = tid >> 2;       // (b,c) group, 0..167
        const int lig = tid & 3;        // lane in group
        const int b = g / NCLS;
        const int c = g % NCLS;
        // 4 threads per (b,c); each sums 128 contiguous partials (32 float4).
        const float4* __restrict__ u4 =
            (const float4*)(ws + (size_t)c * NB + b * BPI + lig * (BPI / 4));
        const float4* __restrict__ i4 =
            (const float4*)(ws + (size_t)(NCLS + c) * NB + b * BPI + lig * (BPI / 4));
        float u = 0.0f, t = 0.0f;
        #pragma unroll 8
        for (int k = 0; k < BPI / 16; ++k) {
            const float4 a = u4[k];
            u += a.x + a.y + a.z + a.w;
            const float4 d = i4[k];
            t += d.x + d.y + d.z + d.w;
        }
        // combine the 4-lane group (aligned within a wave; xor stays in group)
        u += __shfl_xor(u, 1); u += __shfl_xor(u, 2);
        t += __shfl_xor(t, 1); t += __shfl_xor(t, 2);
        if (lig == 0) {
            const float ratio = t / fmaxf(u, 1.0f);
            const float d = ratio - 1.0f;
            val = d * d;
        }
    }
    // block reduction: wave-shuffle then 16-partial LDS combine
    __shared__ float s_w[FBLOCK / 64];
    float v = val;
    #pragma unroll
    for (int off = 32; off > 0; off >>= 1) v += __shfl_down(v, off);
    if ((tid & 63) == 0) s_w[tid >> 6] = v;
    __syncthreads();
    if (tid < 64) {
        float w = (tid < FBLOCK / 64) ? s_w[tid] : 0.0f;
        #pragma unroll
        for (int off = 8; off > 0; off >>= 1) w += __shfl_down(w, off);
        if (tid == 0) out[0] = w / (float)BATCH;
    }
}

extern "C" void kernel_launch(void* const* d_in, const int* in_sizes, int n_in,
                              void* d_out, int out_size, void* d_ws, size_t ws_size,
                              hipStream_t stream) {
    const float* in  = (const float*)d_in[0];
    const int*   tgt = (const int*)d_in[1];
    float* ws  = (float*)d_ws;
    float* out = (float*)d_out;

    dim3 grid(BPI, BATCH);
    iou_partial_kernel<<<grid, BLOCK, 0, stream>>>(in, tgt, ws);
    finalize_kernel<<<1, FBLOCK, 0, stream>>>(ws, out);
}

// Round 3
// 251.014 us; speedup vs baseline: 1.0580x; 1.0580x over previous
//
#include <hip/hip_runtime.h>

#define NCLS 21
#define HW (512 * 512)
#define NP (HW / 2)          // 131072 pixel-pairs per image
#define BATCH 8
#define BLOCK 256
#define BPI (NP / BLOCK)     // 512 blocks per image
#define NB (BATCH * BPI)     // 4096 partial columns
#define NROWS (2 * NCLS)     // 42 partial rows

// ws layout (floats): ws[r * NB + col], r in [0,42)
//   r <  21 : union partial for class r
//   r >= 21 : intersect partial for class r-21
//   col = b * BPI + blk  (each block overwrites its own column; no pre-zero needed)
// Row geometry: one row = 4096 floats = 1024 float4; batch b owns f4-range
// [b*128, (b+1)*128) within the row. This is what finalize's wave sweep exploits.

__global__ __launch_bounds__(BLOCK) void iou_partial_kernel(
        const float* __restrict__ in,   // [B, C, H, W] fp32 logits
        const int*   __restrict__ tgt,  // [B, H, W] int32 labels
        float* __restrict__ ws) {
    const int b   = blockIdx.y;
    const int blk = blockIdx.x;
    const float2* __restrict__ in2 = (const float2*)(in + (size_t)b * NCLS * HW);
    const int2*   __restrict__ tb2 = (const int2*)(tgt + (size_t)b * HW);

    __shared__ float s_u[NCLS];
    __shared__ float s_i[NCLS];
    if (threadIdx.x < NCLS) { s_u[threadIdx.x] = 0.0f; s_i[threadIdx.x] = 0.0f; }
    __syncthreads();

    const int p = blk * BLOCK + threadIdx.x;   // pair index (coalesced, 8 B/lane)

    const int2 t2 = tb2[p];
    float2 x[NCLS];
    #pragma unroll
    for (int c = 0; c < NCLS; ++c)
        x[c] = in2[(size_t)c * NP + p];

    const int t[2] = {t2.x, t2.y};
    #pragma unroll
    for (int j = 0; j < 2; ++j) {
        const int tj = t[j];
        // pass 1: max + argmax (strict >, first index on tie)
        float m  = (j == 0) ? x[0].x : x[0].y;
        int   aj = 0;
        #pragma unroll
        for (int c = 1; c < NCLS; ++c) {
            const float v = (j == 0) ? x[c].x : x[c].y;
            const bool g = v > m;
            aj = g ? c : aj;
            m  = g ? v : m;
        }
        // pass 2: sum of exp + select e_target in the same sweep
        float s  = 0.0f;
        float et = 0.0f;
        #pragma unroll
        for (int c = 0; c < NCLS; ++c) {
            const float v = (j == 0) ? x[c].x : x[c].y;
            const float e = __expf(v - m);
            s += e;
            et = (c == tj) ? e : et;
        }
        const float p_pred = 1.0f / s;        // exp(m-m)/s
        const float p_t    = et * p_pred;
        const bool  eq = (tj == aj);
        // union 2->1 clamp: if eq, one union add + one intersect add;
        // else two union adds. Exactly 2 LDS atomics/pixel, branchless.
        atomicAdd(&s_u[aj], p_pred);
        atomicAdd(eq ? &s_i[aj] : &s_u[tj], eq ? p_pred : p_t);
    }

    __syncthreads();
    // Non-atomic per-block partial write: 42 scattered dwords per block.
    if (threadIdx.x < NROWS) {
        const float v = (threadIdx.x < NCLS) ? s_u[threadIdx.x]
                                             : s_i[threadIdx.x - NCLS];
        ws[(size_t)threadIdx.x * NB + b * BPI + blk] = v;
    }
}

#define FBLOCK 1024
#define FWAVES (FBLOCK / 64)   // 16

__global__ __launch_bounds__(FBLOCK) void finalize_kernel(
        const float* __restrict__ ws, float* __restrict__ out) {
    __shared__ float s_sum[NROWS][BATCH];   // per-(row, batch) totals
    __shared__ float s_red[FWAVES];
    const int tid  = threadIdx.x;
    const int w    = tid >> 6;
    const int lane = tid & 63;
    const float4* __restrict__ ws4 = (const float4*)ws;

    // Wave w sweeps rows r = w, w+16, w+32. One row = 1024 float4 = 16 f4/lane,
    // lane-contiguous (fully coalesced, L2-resident). f4-index i*64+lane lies
    // entirely within batch i/2's 128-f4 segment, so the per-lane bucket index
    // i>>1 is wave-uniform.
    for (int r = w; r < NROWS; r += FWAVES) {
        float acc[BATCH];
        #pragma unroll
        for (int b = 0; b < BATCH; ++b) acc[b] = 0.0f;
        #pragma unroll
        for (int i = 0; i < 16; ++i) {
            const float4 v = ws4[(size_t)r * (NB / 4) + i * 64 + lane];
            acc[i >> 1] += v.x + v.y + v.z + v.w;
        }
        #pragma unroll
        for (int b = 0; b < BATCH; ++b) {
            float v = acc[b];
            #pragma unroll
            for (int off = 32; off > 0; off >>= 1) v += __shfl_xor(v, off);
            acc[b] = v;
        }
        if (lane == 0) {
            #pragma unroll
            for (int b = 0; b < BATCH; ++b) s_sum[r][b] = acc[b];
        }
    }
    __syncthreads();

    // 168 threads compute per-(b,c) squared error; block-reduce; mean over batch.
    float val = 0.0f;
    if (tid < BATCH * NCLS) {
        const int b = tid / NCLS;
        const int c = tid % NCLS;
        const float u  = s_sum[c][b];
        const float it = s_sum[NCLS + c][b];
        const float ratio = it / fmaxf(u, 1.0f);
        const float d = ratio - 1.0f;
        val = d * d;
    }
    float v = val;
    #pragma unroll
    for (int off = 32; off > 0; off >>= 1) v += __shfl_xor(v, off);
    if (lane == 0) s_red[w] = v;
    __syncthreads();
    if (tid < 64) {
        float x = (tid < FWAVES) ? s_red[tid] : 0.0f;
        #pragma unroll
        for (int off = 8; off > 0; off >>= 1) x += __shfl_xor(x, off);
        if (tid == 0) out[0] = x / (float)BATCH;
    }
}

extern "C" void kernel_launch(void* const* d_in, const int* in_sizes, int n_in,
                              void* d_out, int out_size, void* d_ws, size_t ws_size,
                              hipStream_t stream) {
    const float* in  = (const float*)d_in[0];
    const int*   tgt = (const int*)d_in[1];
    float* ws  = (float*)d_ws;
    float* out = (float*)d_out;

    dim3 grid(BPI, BATCH);
    iou_partial_kernel<<<grid, BLOCK, 0, stream>>>(in, tgt, ws);
    finalize_kernel<<<1, FBLOCK, 0, stream>>>(ws, out);
}